// Round 3
// baseline (180.078 us; speedup 1.0000x reference)
//
#include <hip/hip_runtime.h>

#define B_    8
#define D_IN  256
#define D_HID 1024
#define D_OUT 40000       // = 200*200
#define HW4   10000       // D_OUT/4

typedef float f32x4 __attribute__((ext_vector_type(4)));

// Kernel 1: hT[k*8+b] = leakyrelu(loc[b,:] @ W1[:,k] + b1[k])
__global__ void mlp1_kernel(const float* __restrict__ loc,
                            const float* __restrict__ W1,
                            const float* __restrict__ b1,
                            float* __restrict__ hT) {
    int tid = blockIdx.x * blockDim.x + threadIdx.x;   // 8192 threads
    if (tid >= B_ * D_HID) return;
    int b = tid >> 10;
    int k = tid & 1023;
    float acc = b1[k];
    #pragma unroll 8
    for (int i = 0; i < D_IN; ++i)
        acc += loc[b * D_IN + i] * W1[i * D_HID + k];
    acc = (acc >= 0.0f) ? acc : 0.1f * acc;
    hT[k * B_ + b] = acc;
}

// Kernel 2a: split-K partial, float4 over columns.
// partial4[(ks*8+b)*HW4 + j4] = sum_{k in chunk} hT[k][b] * W2[k][j4*4..+3]
__global__ void mlp2_partial_kernel(const float* __restrict__ hT,
                                    const float* __restrict__ W2,
                                    float* __restrict__ partial,
                                    int chunk) {
    int j4 = blockIdx.x * blockDim.x + threadIdx.x;
    if (j4 >= HW4) return;
    int ks = blockIdx.y;
    int k0 = ks * chunk;
    const f32x4* __restrict__ W24 = (const f32x4*)W2;
    f32x4 acc[B_];
    #pragma unroll
    for (int b = 0; b < B_; ++b) acc[b] = (f32x4)0.0f;
    #pragma unroll 8
    for (int kk = 0; kk < chunk; ++kk) {
        int k = k0 + kk;
        f32x4 wv = W24[k * HW4 + j4];          // 16B/lane, coalesced
        const float* __restrict__ h = &hT[k * B_];  // wave-uniform
        #pragma unroll
        for (int b = 0; b < B_; ++b)
            acc[b] += wv * h[b];
    }
    f32x4* __restrict__ p4 = (f32x4*)partial;
    #pragma unroll
    for (int b = 0; b < B_; ++b)
        p4[(ks * B_ + b) * HW4 + j4] = acc[b];
}

// Kernel 2b: reduce partials + bias, write 1+w (vectorized)
__global__ void mlp2_reduce_kernel(const float* __restrict__ partial,
                                   const float* __restrict__ b2,
                                   float* __restrict__ wmap,
                                   int KS) {
    int t = blockIdx.x * blockDim.x + threadIdx.x;   // over 80000
    if (t >= B_ * HW4) return;
    int b = t / HW4;
    int j4 = t - b * HW4;
    const f32x4* __restrict__ p4  = (const f32x4*)partial;
    const f32x4* __restrict__ b24 = (const f32x4*)b2;
    f32x4 s = b24[j4] + 1.0f;
    for (int ks = 0; ks < KS; ++ks)
        s += p4[(ks * B_ + b) * HW4 + j4];
    ((f32x4*)wmap)[b * HW4 + j4] = s;
}

// Kernel 3: out = x * wmap_broadcast. One block per (b,c) plane — no division.
__global__ void scale_kernel(const float* __restrict__ x,
                             const float* __restrict__ wmap,
                             float* __restrict__ out) {
    int plane = blockIdx.x;                 // b*256 + c
    int b = plane >> 8;
    const f32x4* __restrict__ x4 = (const f32x4*)x + (size_t)plane * HW4;
    f32x4* __restrict__ o4 = (f32x4*)out + (size_t)plane * HW4;
    const f32x4* __restrict__ w4 = (const f32x4*)wmap + (size_t)b * HW4;
    for (int p = threadIdx.x; p < HW4; p += 256) {
        f32x4 xv = __builtin_nontemporal_load(&x4[p]);
        f32x4 wv = w4[p];                   // L2-resident (1.28 MB)
        __builtin_nontemporal_store(xv * wv, &o4[p]);
    }
}

extern "C" void kernel_launch(void* const* d_in, const int* in_sizes, int n_in,
                              void* d_out, int out_size, void* d_ws, size_t ws_size,
                              hipStream_t stream) {
    const float* x   = (const float*)d_in[0];
    const float* loc = (const float*)d_in[1];
    const float* W1  = (const float*)d_in[2];
    const float* b1  = (const float*)d_in[3];
    const float* W2  = (const float*)d_in[4];
    const float* b2  = (const float*)d_in[5];
    float* out = (float*)d_out;

    float* hT      = (float*)d_ws;                       // 32 KB
    float* partial = (float*)((char*)d_ws + 32768);
    // wmap lives after the largest possible partial (KS=8 -> 10.24 MB)

    size_t base = 32768;
    int KS = 1;
    for (int cand = 8; cand >= 1; cand >>= 1) {
        size_t need = base + (size_t)cand * B_ * D_OUT * sizeof(float)
                    + (size_t)B_ * D_OUT * sizeof(float);
        if (need <= ws_size) { KS = cand; break; }
    }
    int chunk = D_HID / KS;
    float* wmap = (float*)((char*)d_ws + base
                           + (size_t)KS * B_ * D_OUT * sizeof(float));

    mlp1_kernel<<<32, 256, 0, stream>>>(loc, W1, b1, hT);

    dim3 g2((HW4 + 255) / 256, KS);
    mlp2_partial_kernel<<<g2, 256, 0, stream>>>(hT, W2, partial, chunk);

    mlp2_reduce_kernel<<<(B_ * HW4 + 255) / 256, 256, 0, stream>>>(partial, b2, wmap, KS);

    scale_kernel<<<2048, 256, 0, stream>>>(x, wmap, out);
}